// Round 1
// baseline (1336.608 us; speedup 1.0000x reference)
//
#include <hip/hip_runtime.h>
#include <stdint.h>

// Problem constants (GatedGraphConv_26585847562966)
#define NN  100000   // nodes
#define DD  128      // feature dim
#define TT  3        // timesteps
#define ETT 4        // edge types
#define EE  250000   // edges per type

typedef float  f32x4  __attribute__((ext_vector_type(4)));
typedef __bf16 bf16x8 __attribute__((ext_vector_type(8)));

__device__ __forceinline__ float bf2f(uint32_t u){ u <<= 16; return __builtin_bit_cast(float, u); }
__device__ __forceinline__ uint32_t f2bf(float f){
  uint32_t u = __builtin_bit_cast(uint32_t, f);
  return (u + 0x7FFFu + ((u >> 16) & 1u)) >> 16;   // RNE, low 16 bits valid
}
__device__ __forceinline__ f32x4 mfma16(bf16x8 a, bf16x8 b, f32x4 c){
  return __builtin_amdgcn_mfma_f32_16x16x32_bf16(a, b, c, 0, 0, 0);
}

// ---------------------------------------------------------------- CSR build
__global__ void k_count(const int* __restrict__ erow, const float* __restrict__ eval,
                        int* __restrict__ counts, float* __restrict__ degval){
  int idx = blockIdx.x * 256 + threadIdx.x;
  if (idx >= ETT * EE) return;
  int e = idx / EE;
  int row = erow[idx];
  atomicAdd(&counts[e * NN + row], 1);
  atomicAdd(&degval[e * NN + row], eval[idx]);
}

__global__ void k_scan(const int* __restrict__ counts, int* __restrict__ offsets){
  const int e = blockIdx.x;
  const int* c = counts + e * NN;
  int* off = offsets + e * (NN + 1);
  __shared__ int wtot[16], wexc[16];
  __shared__ int s_running, s_ctot;
  const int t = threadIdx.x, lane = t & 63, wid = t >> 6;
  if (t == 0) s_running = 0;
  __syncthreads();
  for (int base = 0; base < NN; base += 8192){
    int v[8], pre[8]; int s = 0;
    #pragma unroll
    for (int i = 0; i < 8; ++i){
      int idx = base + t * 8 + i;
      int x = (idx < NN) ? c[idx] : 0;
      v[i] = x; s += x; pre[i] = s;
    }
    int x = s;
    #pragma unroll
    for (int d = 1; d < 64; d <<= 1){ int y = __shfl_up(x, d); if (lane >= d) x += y; }
    if (lane == 63) wtot[wid] = x;
    __syncthreads();
    if (wid == 0 && lane < 16){
      int w0 = wtot[lane]; int xx = w0;
      #pragma unroll
      for (int d = 1; d < 16; d <<= 1){ int y = __shfl_up(xx, d); if (lane >= d) xx += y; }
      wexc[lane] = xx - w0;
      if (lane == 15) s_ctot = xx;
    }
    __syncthreads();
    const int myexc = s_running + wexc[wid] + (x - s);
    #pragma unroll
    for (int i = 0; i < 8; ++i){
      int idx = base + t * 8 + i;
      if (idx < NN) off[idx] = myexc + pre[i] - v[i];
    }
    __syncthreads();
    if (t == 0) s_running += s_ctot;
    __syncthreads();
  }
  if (t == 0) off[NN] = s_running;
}

__global__ void k_fill(const int* __restrict__ erow, const int* __restrict__ ecol,
                       const float* __restrict__ eval, const int* __restrict__ offsets,
                       int* __restrict__ cursor, int* __restrict__ scol, float* __restrict__ sval){
  int idx = blockIdx.x * 256 + threadIdx.x;
  if (idx >= ETT * EE) return;
  int e = idx / EE;
  int row = erow[idx];
  int pos = atomicAdd(&cursor[e * NN + row], 1);
  int o = offsets[e * (NN + 1) + row] + pos;
  scol[e * EE + o] = ecol[idx];
  sval[e * EE + o] = eval[idx];
}

// ---------------------------------------------------------------- converts
__global__ void k_conv_x(const float* __restrict__ x, uint16_t* __restrict__ hbf){
  int idx = blockIdx.x * 256 + threadIdx.x;       // one uint4 (8 bf16) per thread
  const float4* xp = (const float4*)x;
  float4 a = xp[idx * 2], b = xp[idx * 2 + 1];
  uint32_t p0 = f2bf(a.x) | (f2bf(a.y) << 16);
  uint32_t p1 = f2bf(a.z) | (f2bf(a.w) << 16);
  uint32_t p2 = f2bf(b.x) | (f2bf(b.y) << 16);
  uint32_t p3 = f2bf(b.z) | (f2bf(b.w) << 16);
  ((uint4*)hbf)[idx] = make_uint4(p0, p1, p2, p3);
}

// wcatT[t][f][e*128+d] = weight[t][e][d][f]   (B^T layout: contiguous-k fragments)
__global__ void k_conv_w(const float* __restrict__ weight, const float* __restrict__ wih,
                         const float* __restrict__ whh, uint16_t* __restrict__ wcatT,
                         uint16_t* __restrict__ wihb, uint16_t* __restrict__ whhb){
  int idx = blockIdx.x * 256 + threadIdx.x;
  if (idx < TT * 128 * 512){
    int t = idx / 65536; int rem = idx - t * 65536;
    int f = rem >> 9; int u = rem & 511;
    int e = u >> 7; int d = u & 127;
    wcatT[idx] = (uint16_t)f2bf(weight[(((t * 4 + e) * 128 + d) << 7) + f]);
  }
  if (idx < 384 * 128){
    wihb[idx] = (uint16_t)f2bf(wih[idx]);
    whhb[idx] = (uint16_t)f2bf(whh[idx]);
  }
}

// ------------------------------------------------- fused gather + GEMM1
// m_sum[n,f] = sum_{e,d} agg[e,n,d] * W[t,e,d,f] + sum_e deg[e,n]*bias_w[t,e,f]
__global__ __launch_bounds__(256) void k_agg_gemm(
    const uint16_t* __restrict__ hbf, const int* __restrict__ offsets,
    const int* __restrict__ scol, const float* __restrict__ sval,
    const float* __restrict__ degval, const float* __restrict__ bias_w,
    const uint16_t* __restrict__ wcatT_t, int tstep, uint16_t* __restrict__ m_out)
{
  __shared__ uint16_t aggT[64 * 512];             // 64 KiB, 16B-chunk XOR-swizzled
  const int tid = threadIdx.x;
  const int node0 = blockIdx.x * 64;

  { // gather: thread = (node nl, quarter q of 32 dims)
    const int nl = tid >> 2, q = tid & 3;
    const int n = node0 + nl;
    #pragma unroll 1
    for (int e = 0; e < ETT; ++e){
      float acc[32];
      #pragma unroll
      for (int i = 0; i < 32; ++i) acc[i] = 0.f;
      if (n < NN){
        const int s  = offsets[e * (NN + 1) + n];
        const int en = offsets[e * (NN + 1) + n + 1];
        for (int i = s; i < en; ++i){
          const int   col = scol[e * EE + i];
          const float val = sval[e * EE + i];
          const uint4* hp = (const uint4*)(hbf + (size_t)col * DD + q * 32);
          #pragma unroll
          for (int c4 = 0; c4 < 4; ++c4){
            uint4 u = hp[c4];
            acc[c4*8+0] += val * bf2f(u.x & 0xffffu);
            acc[c4*8+1] += val * bf2f(u.x >> 16);
            acc[c4*8+2] += val * bf2f(u.y & 0xffffu);
            acc[c4*8+3] += val * bf2f(u.y >> 16);
            acc[c4*8+4] += val * bf2f(u.z & 0xffffu);
            acc[c4*8+5] += val * bf2f(u.z >> 16);
            acc[c4*8+6] += val * bf2f(u.w & 0xffffu);
            acc[c4*8+7] += val * bf2f(u.w >> 16);
          }
        }
      }
      #pragma unroll
      for (int c4 = 0; c4 < 4; ++c4){
        const int c  = e * 16 + q * 4 + c4;       // logical 16B chunk (0..63)
        const int cs = c ^ (nl & 7);
        uint32_t p0 = f2bf(acc[c4*8+0]) | (f2bf(acc[c4*8+1]) << 16);
        uint32_t p1 = f2bf(acc[c4*8+2]) | (f2bf(acc[c4*8+3]) << 16);
        uint32_t p2 = f2bf(acc[c4*8+4]) | (f2bf(acc[c4*8+5]) << 16);
        uint32_t p3 = f2bf(acc[c4*8+6]) | (f2bf(acc[c4*8+7]) << 16);
        *(uint4*)&aggT[nl * 512 + cs * 8] = make_uint4(p0, p1, p2, p3);
      }
    }
  }
  __syncthreads();

  // GEMM: C[64x128] = aggT[64x512] * Wcat[512x128]; wave w owns rows 16w..16w+15
  const int lane = tid & 63, w = tid >> 6;
  const int rlo = lane & 15, kg = lane >> 4;
  const int rowA = w * 16 + rlo;
  f32x4 C[8];
  #pragma unroll
  for (int i = 0; i < 8; ++i) C[i] = f32x4{0.f, 0.f, 0.f, 0.f};

  #pragma unroll 1
  for (int ks = 0; ks < 16; ++ks){
    const int cs = (ks * 4 + kg) ^ (rowA & 7);
    bf16x8 a = __builtin_bit_cast(bf16x8, *(const uint4*)&aggT[rowA * 512 + cs * 8]);
    const uint16_t* bb = wcatT_t + rlo * 512 + ks * 32 + kg * 8;
    #pragma unroll
    for (int ft = 0; ft < 8; ++ft){
      bf16x8 b = __builtin_bit_cast(bf16x8, *(const uint4*)(bb + ft * 16 * 512));
      C[ft] = mfma16(a, b, C[ft]);
    }
  }

  const float* bwt = bias_w + tstep * (ETT * DD);
  #pragma unroll
  for (int ft = 0; ft < 8; ++ft){
    const int f = ft * 16 + rlo;
    const float b0 = bwt[0*DD + f], b1 = bwt[1*DD + f], b2 = bwt[2*DD + f], b3 = bwt[3*DD + f];
    #pragma unroll
    for (int r = 0; r < 4; ++r){
      const int n2 = node0 + w * 16 + kg * 4 + r;
      if (n2 < NN){
        const float bias = degval[0*NN + n2] * b0 + degval[1*NN + n2] * b1
                         + degval[2*NN + n2] * b2 + degval[3*NN + n2] * b3;
        m_out[(size_t)n2 * DD + f] = (uint16_t)f2bf(C[ft][r] + bias);
      }
    }
  }
}

// ------------------------------------------------- fused GRU (gi^T/gh^T MFMA + gates)
__global__ __launch_bounds__(256) void k_gru(
    const uint16_t* __restrict__ m_sum, uint16_t* __restrict__ hbf,
    const float* __restrict__ h_old, float* __restrict__ h_new,
    const uint16_t* __restrict__ wihb, const uint16_t* __restrict__ whhb,
    const float* __restrict__ b_ih, const float* __restrict__ b_hh)
{
  __shared__ uint16_t mT[16 * 128];
  __shared__ uint16_t hT[16 * 128];
  __shared__ float G[768 * 17];                   // [gate j 0..767][node 0..15], pad 17
  __shared__ float bI[384], bH[384];
  const int tid = threadIdx.x;
  const int node0 = blockIdx.x * 16;

  { // stage m_sum/h tiles (swizzled for B-fragment reads)
    const int row = tid >> 4, c = tid & 15;
    const int cs = c ^ (row & 7);
    uint4 mv = *(const uint4*)(m_sum + (size_t)(node0 + row) * DD + c * 8);
    uint4 hv = *(const uint4*)(hbf  + (size_t)(node0 + row) * DD + c * 8);
    *(uint4*)&mT[row * 128 + cs * 8] = mv;
    *(uint4*)&hT[row * 128 + cs * 8] = hv;
  }
  for (int i = tid; i < 384; i += 256){ bI[i] = b_ih[i]; bH[i] = b_hh[i]; }
  __syncthreads();

  const int lane = tid & 63, w = tid >> 6;
  const int rlo = lane & 15, kg = lane >> 4;
  f32x4 ai[6], ah[6];
  #pragma unroll
  for (int i = 0; i < 6; ++i){ ai[i] = f32x4{0.f,0.f,0.f,0.f}; ah[i] = f32x4{0.f,0.f,0.f,0.f}; }

  #pragma unroll 1
  for (int ks = 0; ks < 4; ++ks){
    const int cs = (ks * 4 + kg) ^ (rlo & 7);
    bf16x8 bm = __builtin_bit_cast(bf16x8, *(const uint4*)&mT[rlo * 128 + cs * 8]);
    bf16x8 bh = __builtin_bit_cast(bf16x8, *(const uint4*)&hT[rlo * 128 + cs * 8]);
    #pragma unroll
    for (int j6 = 0; j6 < 6; ++j6){
      const int j = (w * 6 + j6) * 16 + rlo;      // A row = gate index
      bf16x8 fa = __builtin_bit_cast(bf16x8, *(const uint4*)(wihb + j * 128 + ks * 32 + kg * 8));
      ai[j6] = mfma16(fa, bm, ai[j6]);
      bf16x8 fb = __builtin_bit_cast(bf16x8, *(const uint4*)(whhb + j * 128 + ks * 32 + kg * 8));
      ah[j6] = mfma16(fb, bh, ah[j6]);
    }
  }
  #pragma unroll
  for (int j6 = 0; j6 < 6; ++j6){
    #pragma unroll
    for (int r = 0; r < 4; ++r){
      const int j = (w * 6 + j6) * 16 + kg * 4 + r;
      G[j * 17 + rlo]         = ai[j6][r];
      G[(384 + j) * 17 + rlo] = ah[j6][r];
    }
  }
  __syncthreads();

  const int d = tid & 127, nb = tid >> 7;
  #pragma unroll
  for (int i = 0; i < 8; ++i){
    const int n = nb * 8 + i;
    const float ir = G[d * 17 + n]          + bI[d];
    const float iz = G[(128 + d) * 17 + n]  + bI[128 + d];
    const float ig = G[(256 + d) * 17 + n]  + bI[256 + d];
    const float hr = G[(384 + d) * 17 + n]  + bH[d];
    const float hz = G[(512 + d) * 17 + n]  + bH[128 + d];
    const float hg = G[(640 + d) * 17 + n]  + bH[256 + d];
    const float r  = 1.f / (1.f + __expf(-(ir + hr)));
    const float z  = 1.f / (1.f + __expf(-(iz + hz)));
    const float xa = ig + r * hg;
    const float nn = 1.f - 2.f / (__expf(2.f * xa) + 1.f);   // tanh
    const size_t gidx = (size_t)(node0 + n) * DD + d;
    const float hv = (1.f - z) * nn + z * h_old[gidx];
    h_new[gidx] = hv;
    hbf[gidx]   = (uint16_t)f2bf(hv);
  }
}

// ---------------------------------------------------------------- launch
extern "C" void kernel_launch(void* const* d_in, const int* in_sizes, int n_in,
                              void* d_out, int out_size, void* d_ws, size_t ws_size,
                              hipStream_t stream) {
  const float* x      = (const float*)d_in[0];
  const int*   erow   = (const int*)d_in[1];
  const int*   ecol   = (const int*)d_in[2];
  const float* eval   = (const float*)d_in[3];
  const float* weight = (const float*)d_in[4];
  const float* bias_w = (const float*)d_in[5];
  const float* wih    = (const float*)d_in[6];
  const float* whh    = (const float*)d_in[7];
  const float* bih    = (const float*)d_in[8];
  const float* bhh    = (const float*)d_in[9];
  float* out = (float*)d_out;
  char* ws = (char*)d_ws;

  size_t o = 0;
  auto alloc = [&](size_t bytes)->char*{ char* p = ws + o; o += (bytes + 255) & ~(size_t)255; return p; };
  int*      counts  = (int*)     alloc((size_t)ETT * NN * 4);        // zeroed
  int*      cursor  = (int*)     alloc((size_t)ETT * NN * 4);        // zeroed
  float*    degval  = (float*)   alloc((size_t)ETT * NN * 4);        // zeroed
  int*      offsets = (int*)     alloc((size_t)ETT * (NN + 1) * 4);
  int*      scol    = (int*)     alloc((size_t)ETT * EE * 4);
  float*    sval    = (float*)   alloc((size_t)ETT * EE * 4);
  float*    hf      = (float*)   alloc((size_t)NN * DD * 4);
  uint16_t* hbf     = (uint16_t*)alloc((size_t)NN * DD * 2);
  uint16_t* msum    = (uint16_t*)alloc((size_t)NN * DD * 2);
  uint16_t* wcatT   = (uint16_t*)alloc((size_t)TT * 128 * 512 * 2);
  uint16_t* wihb    = (uint16_t*)alloc((size_t)384 * 128 * 2);
  uint16_t* whhb    = (uint16_t*)alloc((size_t)384 * 128 * 2);
  (void)ws_size; (void)in_sizes; (void)n_in; (void)out_size;

  // counts/cursor/degval are contiguous (each 1.6MB, 256-aligned exactly)
  hipMemsetAsync(counts, 0, (size_t)3 * ETT * NN * 4, stream);

  k_count<<<(ETT * EE + 255) / 256, 256, 0, stream>>>(erow, eval, counts, degval);
  k_scan<<<ETT, 1024, 0, stream>>>(counts, offsets);
  k_fill<<<(ETT * EE + 255) / 256, 256, 0, stream>>>(erow, ecol, eval, offsets, cursor, scol, sval);
  k_conv_x<<<(NN * DD / 8) / 256, 256, 0, stream>>>(x, hbf);
  k_conv_w<<<(TT * 128 * 512 + 255) / 256, 256, 0, stream>>>(weight, wih, whh, wcatT, wihb, whhb);

  for (int t = 0; t < TT; ++t){
    k_agg_gemm<<<(NN + 63) / 64, 256, 0, stream>>>(hbf, offsets, scol, sval, degval,
                                                   bias_w, wcatT + (size_t)t * 65536, t, msum);
    const float* hold = (t == 0) ? x : hf;
    float* hnew = (t == TT - 1) ? out : hf;
    k_gru<<<NN / 16, 256, 0, stream>>>(msum, hbf, hold, hnew, wihb, whhb, bih, bhh);
  }
}

// Round 2
// 1236.642 us; speedup vs baseline: 1.0808x; 1.0808x over previous
//
#include <hip/hip_runtime.h>
#include <stdint.h>

// Problem constants (GatedGraphConv_26585847562966)
#define NN  100000   // nodes
#define DD  128      // feature dim
#define TT  3        // timesteps
#define ETT 4        // edge types
#define EE  250000   // edges per type
#define NCH 49       // scan chunks per edge type (2048 elems each)

typedef float  f32x4  __attribute__((ext_vector_type(4)));
typedef __bf16 bf16x8 __attribute__((ext_vector_type(8)));

__device__ __forceinline__ float bf2f(uint32_t u){ u <<= 16; return __builtin_bit_cast(float, u); }
__device__ __forceinline__ uint32_t f2bf(float f){
  uint32_t u = __builtin_bit_cast(uint32_t, f);
  return (u + 0x7FFFu + ((u >> 16) & 1u)) >> 16;   // RNE, low 16 bits valid
}
__device__ __forceinline__ f32x4 mfma16(bf16x8 a, bf16x8 b, f32x4 c){
  return __builtin_amdgcn_mfma_f32_16x16x32_bf16(a, b, c, 0, 0, 0);
}

// ---------------------------------------------------------------- CSR build
__global__ void k_count(const int* __restrict__ erow, const float* __restrict__ eval,
                        int* __restrict__ counts, float* __restrict__ degval){
  int idx = blockIdx.x * 256 + threadIdx.x;
  if (idx >= ETT * EE) return;
  int e = idx / EE;
  int row = erow[idx];
  atomicAdd(&counts[e * NN + row], 1);
  atomicAdd(&degval[e * NN + row], eval[idx]);
}

// per-chunk sums (grid = ETT*NCH blocks x 256)
__global__ void k_blksum(const int* __restrict__ counts, int* __restrict__ bsum){
  const int b = blockIdx.x, e = b / NCH, c = b % NCH;
  const int* p = counts + e * NN + c * 2048;
  int lim = NN - c * 2048; if (lim > 2048) lim = 2048;
  const int t = threadIdx.x;
  int s = 0;
  #pragma unroll
  for (int i = 0; i < 8; ++i){
    int idx = i * 256 + t;
    if (idx < lim) s += p[idx];
  }
  #pragma unroll
  for (int d = 32; d; d >>= 1) s += __shfl_down(s, d);
  __shared__ int wsum[4];
  if ((t & 63) == 0) wsum[t >> 6] = s;
  __syncthreads();
  if (t == 0) bsum[b] = wsum[0] + wsum[1] + wsum[2] + wsum[3];
}

// scan the 49 chunk-sums per edge type (1 block, wave per etype)
__global__ void k_scanp(const int* __restrict__ bsum, int* __restrict__ bexc,
                        int* __restrict__ offsets){
  const int t = threadIdx.x, wid = t >> 6, l = t & 63;
  int v = (l < NCH) ? bsum[wid * NCH + l] : 0;
  int x = v;
  #pragma unroll
  for (int d = 1; d < 64; d <<= 1){ int y = __shfl_up(x, d); if (l >= d) x += y; }
  if (l < NCH) bexc[wid * NCH + l] = x - v;
  if (l == NCH - 1) offsets[wid * (NN + 1) + NN] = x;
}

// per-chunk exclusive scan + chunk offset (grid = ETT*NCH x 256)
__global__ void k_apply(const int* __restrict__ counts, const int* __restrict__ bexc,
                        int* __restrict__ offsets){
  const int b = blockIdx.x, e = b / NCH, c = b % NCH;
  const int* p = counts + e * NN + c * 2048;
  int* off = offsets + e * (NN + 1) + c * 2048;
  int lim = NN - c * 2048; if (lim > 2048) lim = 2048;
  const int t = threadIdx.x, l = t & 63, wid = t >> 6;
  __shared__ int wt[4];
  int v[8], s = 0;
  #pragma unroll
  for (int i = 0; i < 8; ++i){
    int idx = t * 8 + i;
    v[i] = (idx < lim) ? p[idx] : 0; s += v[i];
  }
  int x = s;
  #pragma unroll
  for (int d = 1; d < 64; d <<= 1){ int y = __shfl_up(x, d); if (l >= d) x += y; }
  if (l == 63) wt[wid] = x;
  __syncthreads();
  int wexc = 0;
  #pragma unroll
  for (int k = 0; k < 4; ++k) if (k < wid) wexc += wt[k];
  int te = bexc[b] + wexc + (x - s);
  #pragma unroll
  for (int i = 0; i < 8; ++i){
    int idx = t * 8 + i;
    if (idx < lim) off[idx] = te;
    te += v[i];
  }
}

__global__ void k_fill(const int* __restrict__ erow, const int* __restrict__ ecol,
                       const float* __restrict__ eval, const int* __restrict__ offsets,
                       int* __restrict__ cursor, uint2* __restrict__ sedge){
  int idx = blockIdx.x * 256 + threadIdx.x;
  if (idx >= ETT * EE) return;
  int e = idx / EE;
  int row = erow[idx];
  int pos = atomicAdd(&cursor[e * NN + row], 1);
  int o = offsets[e * (NN + 1) + row] + pos;
  sedge[e * EE + o] = make_uint2((uint32_t)ecol[idx], __builtin_bit_cast(uint32_t, eval[idx]));
}

// ---------------------------------------------------------------- converts
__global__ void k_conv_x(const float* __restrict__ x, uint16_t* __restrict__ hbf){
  int idx = blockIdx.x * 256 + threadIdx.x;       // one uint4 (8 bf16) per thread
  const float4* xp = (const float4*)x;
  float4 a = xp[idx * 2], b = xp[idx * 2 + 1];
  uint32_t p0 = f2bf(a.x) | (f2bf(a.y) << 16);
  uint32_t p1 = f2bf(a.z) | (f2bf(a.w) << 16);
  uint32_t p2 = f2bf(b.x) | (f2bf(b.y) << 16);
  uint32_t p3 = f2bf(b.z) | (f2bf(b.w) << 16);
  ((uint4*)hbf)[idx] = make_uint4(p0, p1, p2, p3);
}

// wcatT[t][f][e*128+d] = weight[t][e][d][f]   (B^T layout: contiguous-k fragments)
__global__ void k_conv_w(const float* __restrict__ weight, const float* __restrict__ wih,
                         const float* __restrict__ whh, const float* __restrict__ bih,
                         const float* __restrict__ bhh, uint16_t* __restrict__ wcatT,
                         uint16_t* __restrict__ wihb, uint16_t* __restrict__ whhb,
                         float* __restrict__ bcomb){
  int idx = blockIdx.x * 256 + threadIdx.x;
  if (idx < TT * 128 * 512){
    int t = idx / 65536; int rem = idx - t * 65536;
    int f = rem >> 9; int u = rem & 511;
    int e = u >> 7; int d = u & 127;
    wcatT[idx] = (uint16_t)f2bf(weight[(((t * 4 + e) * 128 + d) << 7) + f]);
  }
  if (idx < 384 * 128){
    wihb[idx] = (uint16_t)f2bf(wih[idx]);
    whhb[idx] = (uint16_t)f2bf(whh[idx]);
  }
  if (idx < 256) bcomb[idx] = bih[idx] + bhh[idx];
}

// ------------------------------------------------- fused gather + GEMM1
// m_sum[n,f] = sum_{e,d} agg[e,n,d] * W[t,e,d,f] + sum_e deg[e,n]*bias_w[t,e,f]
__global__ __launch_bounds__(256, 4) void k_agg_gemm(
    const uint16_t* __restrict__ hbf, const int* __restrict__ offsets,
    const uint2* __restrict__ sedge, const float* __restrict__ degval,
    const float* __restrict__ bias_w, const uint16_t* __restrict__ wcatT_t,
    int tstep, uint16_t* __restrict__ m_out)
{
  __shared__ uint16_t aggT[32 * 512];             // 32 KiB, 16B-chunk XOR-swizzled
  const int tid = threadIdx.x;
  const int node0 = blockIdx.x * 32;              // 100000/32 = 3125 blocks exact

  { // gather: thread = (node nl of 32, eighth q of 16 dims)
    const int nl = tid >> 3, q = tid & 7;
    const int n = node0 + nl;
    #pragma unroll 1
    for (int e = 0; e < ETT; ++e){
      float acc[16];
      #pragma unroll
      for (int i = 0; i < 16; ++i) acc[i] = 0.f;
      const int s  = offsets[e * (NN + 1) + n];
      const int en = offsets[e * (NN + 1) + n + 1];
      for (int i = s; i < en; ++i){
        const uint2 cv = sedge[e * EE + i];
        const float val = __builtin_bit_cast(float, cv.y);
        const uint4* hp = (const uint4*)(hbf + (size_t)cv.x * DD + q * 16);
        uint4 u0 = hp[0], u1 = hp[1];
        acc[0]  += val * bf2f(u0.x & 0xffffu);  acc[1]  += val * bf2f(u0.x >> 16);
        acc[2]  += val * bf2f(u0.y & 0xffffu);  acc[3]  += val * bf2f(u0.y >> 16);
        acc[4]  += val * bf2f(u0.z & 0xffffu);  acc[5]  += val * bf2f(u0.z >> 16);
        acc[6]  += val * bf2f(u0.w & 0xffffu);  acc[7]  += val * bf2f(u0.w >> 16);
        acc[8]  += val * bf2f(u1.x & 0xffffu);  acc[9]  += val * bf2f(u1.x >> 16);
        acc[10] += val * bf2f(u1.y & 0xffffu);  acc[11] += val * bf2f(u1.y >> 16);
        acc[12] += val * bf2f(u1.z & 0xffffu);  acc[13] += val * bf2f(u1.z >> 16);
        acc[14] += val * bf2f(u1.w & 0xffffu);  acc[15] += val * bf2f(u1.w >> 16);
      }
      #pragma unroll
      for (int c2 = 0; c2 < 2; ++c2){
        const int c  = e * 16 + q * 2 + c2;       // logical 16B chunk (0..63)
        const int cs = c ^ (nl & 7);
        uint32_t p0 = f2bf(acc[c2*8+0]) | (f2bf(acc[c2*8+1]) << 16);
        uint32_t p1 = f2bf(acc[c2*8+2]) | (f2bf(acc[c2*8+3]) << 16);
        uint32_t p2 = f2bf(acc[c2*8+4]) | (f2bf(acc[c2*8+5]) << 16);
        uint32_t p3 = f2bf(acc[c2*8+6]) | (f2bf(acc[c2*8+7]) << 16);
        *(uint4*)&aggT[nl * 512 + cs * 8] = make_uint4(p0, p1, p2, p3);
      }
    }
  }
  __syncthreads();

  // GEMM: C[32x128] = aggT[32x512] * Wcat[512x128]
  // wave w: row-tile rt = w&1 (16 rows), f-half fh = w>>1 (64 cols = 4 f-tiles)
  const int lane = tid & 63, w = tid >> 6;
  const int rlo = lane & 15, kg = lane >> 4;
  const int rt = w & 1, fh = w >> 1;
  const int rowA = rt * 16 + rlo;
  f32x4 C[4];
  #pragma unroll
  for (int i = 0; i < 4; ++i) C[i] = f32x4{0.f, 0.f, 0.f, 0.f};

  #pragma unroll
  for (int ks = 0; ks < 16; ++ks){
    const int cs = (ks * 4 + kg) ^ (rowA & 7);
    bf16x8 a = __builtin_bit_cast(bf16x8, *(const uint4*)&aggT[rowA * 512 + cs * 8]);
    #pragma unroll
    for (int ft = 0; ft < 4; ++ft){
      const int f = fh * 64 + ft * 16 + rlo;
      bf16x8 b = __builtin_bit_cast(bf16x8, *(const uint4*)(wcatT_t + (size_t)f * 512 + ks * 32 + kg * 8));
      C[ft] = mfma16(a, b, C[ft]);
    }
  }

  const float* bwt = bias_w + tstep * (ETT * DD);
  float dv[4][4];
  #pragma unroll
  for (int r = 0; r < 4; ++r){
    const int n2 = node0 + rt * 16 + kg * 4 + r;
    #pragma unroll
    for (int e = 0; e < 4; ++e) dv[e][r] = degval[e * NN + n2];
  }
  #pragma unroll
  for (int ft = 0; ft < 4; ++ft){
    const int f = fh * 64 + ft * 16 + rlo;
    const float b0 = bwt[f], b1 = bwt[128 + f], b2 = bwt[256 + f], b3 = bwt[384 + f];
    #pragma unroll
    for (int r = 0; r < 4; ++r){
      const int n2 = node0 + rt * 16 + kg * 4 + r;
      const float bias = dv[0][r]*b0 + dv[1][r]*b1 + dv[2][r]*b2 + dv[3][r]*b3;
      m_out[(size_t)n2 * DD + f] = (uint16_t)f2bf(C[ft][r] + bias);
    }
  }
}

// ------------------------------------------------- fused GRU, gates in-register
// j-remap: wave w owns dims [w*32, w*32+32) for ALL 3 gates:
//   tile j6 (0..5): gate g = j6>>1, half b = j6&1, rows j = g*128 + w*32 + b*16 + rlo
// lane (rlo,kg) then holds ir/iz/in/hr/hz/hn for node rlo, d = w*32+b*16+kg*4+r.
__global__ __launch_bounds__(256, 3) void k_gru(
    const uint16_t* __restrict__ m_sum, uint16_t* __restrict__ hbf,
    const float* __restrict__ h_old, float* __restrict__ h_new,
    const uint16_t* __restrict__ wihb, const uint16_t* __restrict__ whhb,
    const float* __restrict__ bcomb, const float* __restrict__ b_ih,
    const float* __restrict__ b_hh)
{
  const int tid = threadIdx.x;
  const int lane = tid & 63, w = tid >> 6;
  const int rlo = lane & 15, kg = lane >> 4;

  #pragma unroll 1
  for (int nt = 0; nt < 4; ++nt){
    const int tile = blockIdx.x * 4 + nt;
    if (tile * 16 >= NN) break;                    // block-uniform
    const int row = tile * 16 + rlo;
    const uint16_t* mrow = m_sum + (size_t)row * DD;
    const uint16_t* hrow = hbf   + (size_t)row * DD;

    f32x4 ai[6], ah[6];
    #pragma unroll
    for (int i = 0; i < 6; ++i){ ai[i] = f32x4{0,0,0,0}; ah[i] = f32x4{0,0,0,0}; }

    #pragma unroll
    for (int ks = 0; ks < 4; ++ks){
      bf16x8 bm = __builtin_bit_cast(bf16x8, *(const uint4*)(mrow + ks * 32 + kg * 8));
      bf16x8 bh = __builtin_bit_cast(bf16x8, *(const uint4*)(hrow + ks * 32 + kg * 8));
      #pragma unroll
      for (int j6 = 0; j6 < 6; ++j6){
        const int jrow = (j6 >> 1) * 128 + w * 32 + (j6 & 1) * 16 + rlo;
        bf16x8 fa = __builtin_bit_cast(bf16x8, *(const uint4*)(wihb + jrow * 128 + ks * 32 + kg * 8));
        ai[j6] = mfma16(fa, bm, ai[j6]);
        bf16x8 fb = __builtin_bit_cast(bf16x8, *(const uint4*)(whhb + jrow * 128 + ks * 32 + kg * 8));
        ah[j6] = mfma16(fb, bh, ah[j6]);
      }
    }
    __syncthreads();   // all waves' hbf reads of this tile done before stores below

    #pragma unroll
    for (int bb = 0; bb < 2; ++bb){
      const int d0 = w * 32 + bb * 16 + kg * 4;
      const f32x4 brz = *(const f32x4*)(bcomb + d0);
      const f32x4 bzz = *(const f32x4*)(bcomb + 128 + d0);
      const f32x4 bin = *(const f32x4*)(b_ih + 256 + d0);
      const f32x4 bhn = *(const f32x4*)(b_hh + 256 + d0);
      const f32x4 ho  = *(const f32x4*)(h_old + (size_t)row * DD + d0);
      float hv[4];
      #pragma unroll
      for (int r = 0; r < 4; ++r){
        const float rg = 1.f / (1.f + __expf(-(ai[bb][r]     + ah[bb][r]     + brz[r])));
        const float zg = 1.f / (1.f + __expf(-(ai[2+bb][r]   + ah[2+bb][r]   + bzz[r])));
        const float xa = (ai[4+bb][r] + bin[r]) + rg * (ah[4+bb][r] + bhn[r]);
        const float ng = 1.f - 2.f / (__expf(2.f * xa) + 1.f);   // tanh
        hv[r] = (1.f - zg) * ng + zg * ho[r];
      }
      *(f32x4*)(h_new + (size_t)row * DD + d0) = f32x4{hv[0], hv[1], hv[2], hv[3]};
      uint32_t p0 = f2bf(hv[0]) | (f2bf(hv[1]) << 16);
      uint32_t p1 = f2bf(hv[2]) | (f2bf(hv[3]) << 16);
      *(uint2*)(hbf + (size_t)row * DD + d0) = make_uint2(p0, p1);
    }
  }
}

// ---------------------------------------------------------------- launch
extern "C" void kernel_launch(void* const* d_in, const int* in_sizes, int n_in,
                              void* d_out, int out_size, void* d_ws, size_t ws_size,
                              hipStream_t stream) {
  const float* x      = (const float*)d_in[0];
  const int*   erow   = (const int*)d_in[1];
  const int*   ecol   = (const int*)d_in[2];
  const float* eval   = (const float*)d_in[3];
  const float* weight = (const float*)d_in[4];
  const float* bias_w = (const float*)d_in[5];
  const float* wih    = (const float*)d_in[6];
  const float* whh    = (const float*)d_in[7];
  const float* bih    = (const float*)d_in[8];
  const float* bhh    = (const float*)d_in[9];
  float* out = (float*)d_out;
  char* ws = (char*)d_ws;

  size_t o = 0;
  auto alloc = [&](size_t bytes)->char*{ char* p = ws + o; o += (bytes + 255) & ~(size_t)255; return p; };
  int*      counts  = (int*)     alloc((size_t)ETT * NN * 4);        // zeroed
  int*      cursor  = (int*)     alloc((size_t)ETT * NN * 4);        // zeroed
  float*    degval  = (float*)   alloc((size_t)ETT * NN * 4);        // zeroed
  int*      offsets = (int*)     alloc((size_t)ETT * (NN + 1) * 4);
  int*      bsum    = (int*)     alloc((size_t)ETT * NCH * 4);
  int*      bexc    = (int*)     alloc((size_t)ETT * NCH * 4);
  uint2*    sedge   = (uint2*)   alloc((size_t)ETT * EE * 8);
  float*    hf      = (float*)   alloc((size_t)NN * DD * 4);
  uint16_t* hbf     = (uint16_t*)alloc((size_t)NN * DD * 2);
  uint16_t* msum    = (uint16_t*)alloc((size_t)NN * DD * 2);
  uint16_t* wcatT   = (uint16_t*)alloc((size_t)TT * 128 * 512 * 2);
  uint16_t* wihb    = (uint16_t*)alloc((size_t)384 * 128 * 2);
  uint16_t* whhb    = (uint16_t*)alloc((size_t)384 * 128 * 2);
  float*    bcomb   = (float*)   alloc((size_t)256 * 4);
  (void)ws_size; (void)in_sizes; (void)n_in; (void)out_size;

  // counts/cursor/degval contiguous (each 1.6MB, 256-aligned exactly)
  hipMemsetAsync(counts, 0, (size_t)3 * ETT * NN * 4, stream);

  k_count<<<(ETT * EE + 255) / 256, 256, 0, stream>>>(erow, eval, counts, degval);
  k_blksum<<<ETT * NCH, 256, 0, stream>>>(counts, bsum);
  k_scanp<<<1, 256, 0, stream>>>(bsum, bexc, offsets);
  k_apply<<<ETT * NCH, 256, 0, stream>>>(counts, bexc, offsets);
  k_fill<<<(ETT * EE + 255) / 256, 256, 0, stream>>>(erow, ecol, eval, offsets, cursor, sedge);
  k_conv_x<<<(NN * DD / 8) / 256, 256, 0, stream>>>(x, hbf);
  k_conv_w<<<(TT * 128 * 512 + 255) / 256, 256, 0, stream>>>(weight, wih, whh, bih, bhh,
                                                             wcatT, wihb, whhb, bcomb);

  for (int t = 0; t < TT; ++t){
    k_agg_gemm<<<NN / 32, 256, 0, stream>>>(hbf, offsets, sedge, degval,
                                            bias_w, wcatT + (size_t)t * 65536, t, msum);
    const float* hold = (t == 0) ? x : hf;
    float* hnew = (t == TT - 1) ? out : hf;
    k_gru<<<(NN / 16 + 3) / 4, 256, 0, stream>>>(msum, hbf, hold, hnew,
                                                 wihb, whhb, bcomb, bih, bhh);
  }
}